// Round 6
// baseline (367.285 us; speedup 1.0000x reference)
//
#include <hip/hip_runtime.h>
#include <math.h>

typedef _Float16 h16;
typedef __attribute__((ext_vector_type(2))) _Float16 h16x2;
typedef __attribute__((ext_vector_type(4))) _Float16 h16x4;
typedef __attribute__((ext_vector_type(8))) _Float16 h16x8;

#define NBATCH 2048
#define NT 64
#define KK 40
#define NL 7
#define SIGMA 0.02f
#define INVLN2 1.4426950408889634f

// LDS layout (units: h16x2 = 4B)
#define OFF_H   0                   // H  [64][44]  (hr,hi), k-contiguous; row0 cols 40..43 = sRed overlay
#define OFF_WAB (64*44)             // W  [64][40]  (wr,wi)
#define OFF_WBA (OFF_WAB + 64*40)   // W  [64][40]  (wi,-wr)
#define OFF_SAB (OFF_WBA + 64*40)   // S^T[40][44]  (sr,-si); G overlay [40][34] (gr pairs)
#define OFF_SBA (OFF_SAB + 40*44)   // S^T[40][44]  (si, sr); G overlay [40][34] (gi pairs)
#define OFF_UP  (OFF_SBA + 40*44)   // U  [64][33]  (u[m],u[m+1]) packed m-pairs
#define LDS_H2  (OFF_UP + 64*33)    // = 13568 h16x2 = 54272 B -> 3 blocks/CU

static __device__ __forceinline__ float DOT2(h16x2 a, h16x2 b, float c) {
#if __has_builtin(__builtin_amdgcn_fdot2)
    return __builtin_amdgcn_fdot2(a, b, c, false);
#else
    return fmaf((float)a.x, (float)b.x, fmaf((float)a.y, (float)b.y, c));
#endif
}
static __device__ __forceinline__ h16x2 PK(float x, float y) {
    h16x2 r; r.x = (h16)x; r.y = (h16)y; return r;
}
// pair extractors: parse-time legal with runtime index; all call sites are in
// fully-unrolled loops so indices constant-fold and SROA keeps regs.
static __device__ __forceinline__ h16x2 GET8(h16x8 v, int i) {
    union { h16x8 w; h16x2 p[4]; } u; u.w = v; return u.p[i];
}
static __device__ __forceinline__ h16x2 GET4(h16x4 v, int i) {
    union { h16x4 w; h16x2 p[2]; } u; u.w = v; return u.p[i];
}

__global__ __launch_bounds__(256, 3) void gpnet_kernel(
    const float* __restrict__ gHr, const float* __restrict__ gHi,
    const float* __restrict__ gEta, const float* __restrict__ gU,
    const float* __restrict__ gB, float* __restrict__ gOut, int outFloats)
{
    __shared__ __align__(16) h16x2 sh[LDS_H2];
    // sRed lives in H-row-0 padding (cols 40..43, never read as H)
    float* sRed = reinterpret_cast<float*>(sh + OFF_H + 40);

    const int tid = threadIdx.x;
    const int wid = tid >> 6;
    const int bb  = blockIdx.x;
    const float* hr = gHr + (size_t)bb * NT * KK;
    const float* hi = gHi + (size_t)bb * NT * KK;

    // B/C/W-ownership tile: rows (n0, n0+1), cols c0..c0+4
    const int n0  = (tid >> 3) << 1;     // 0,2,...,62
    const int c0  = (tid & 7) * 5;       // 0,5,...,35
    const int nn0 = tid >> 3;            // m-pair index for G

    // A-phase tile (first 200 threads): S rows k0..k0+3, cols l0,l0+1
    const int k0 = (tid / 20) * 4;
    const int l0 = (tid % 20) * 2;

    // ---- init: H -> LDS (fp16 packed); W = b[0] in regs; packed W -> LDS; power
    float Wr[2][5], Wi[2][5];
    {
        for (int i = tid; i < NT*KK; i += 256) {
            int n = i / KK, k = i % KK;
            sh[OFF_H + n*44 + k] = PK(hr[i], hi[i]);
        }
        float ps = 0.f;
        #pragma unroll
        for (int i = 0; i < 2; ++i)
            #pragma unroll
            for (int j = 0; j < 5; ++j) {
                float br = gB[(n0+i)*KK + c0 + j];
                Wr[i][j] = br; Wi[i][j] = 0.f;
                sh[OFF_WAB + (n0+i)*40 + c0+j] = PK(br, 0.f);
                sh[OFF_WBA + (n0+i)*40 + c0+j] = PK(0.f, -br);
                ps += br * br;
            }
        #pragma unroll
        for (int off = 32; off; off >>= 1) ps += __shfl_down(ps, off, 64);
        if ((tid & 63) == 0) sRed[wid] = ps;
    }
    __syncthreads();

    for (int t = 1; t < NL; ++t) {
        const float pw   = sRed[0] + sRed[1] + sRed[2] + sRed[3];
        const float cp   = 0.04f * (pw - 1.0f);
        const float etat = gEta[t];

        // early global loads (hidden under A/coeff/B): U[t] (float2 pairs) and b[t]
        float2 ureg[8];
        {
            const float2* u2 = (const float2*)(gU + (size_t)t * NT * NT);
            #pragma unroll
            for (int j = 0; j < 8; ++j) ureg[j] = u2[tid + j*256];
        }
        float breg[2][5];
        #pragma unroll
        for (int i = 0; i < 2; ++i)
            #pragma unroll
            for (int j = 0; j < 5; ++j)
                breg[i][j] = gB[(size_t)t*NT*KK + (n0+i)*KK + c0 + j];

        // ---- A: S[k][l] = sum_n conj(H[n,k]) W[n,l]; write S^T fp16 (two packed forms)
        if (tid < 200) {
            float ar[4][2] = {}, ai[4][2] = {};
            #pragma unroll 2
            for (int n = 0; n < NT; ++n) {
                h16x8 hv  = *(const h16x8*)(sh + OFF_H   + n*44 + k0);
                h16x4 wav = *(const h16x4*)(sh + OFF_WAB + n*40 + l0);
                h16x4 wbv = *(const h16x4*)(sh + OFF_WBA + n*40 + l0);
                h16x2 wa0 = GET4(wav,0), wa1 = GET4(wav,1);
                h16x2 wb0 = GET4(wbv,0), wb1 = GET4(wbv,1);
                #pragma unroll
                for (int i = 0; i < 4; ++i) {
                    h16x2 h_ = GET8(hv,i);
                    ar[i][0] = DOT2(h_, wa0, ar[i][0]);   // hr*wr + hi*wi
                    ar[i][1] = DOT2(h_, wa1, ar[i][1]);
                    ai[i][0] = DOT2(h_, wb0, ai[i][0]);   // hr*wi - hi*wr
                    ai[i][1] = DOT2(h_, wb1, ai[i][1]);
                }
            }
            #pragma unroll
            for (int j = 0; j < 2; ++j) {
                h16x8 sa, sb;
                #pragma unroll
                for (int i = 0; i < 4; ++i) {
                    sa[2*i]   = (h16)ar[i][j];  sa[2*i+1] = (h16)(-ai[i][j]);
                    sb[2*i]   = (h16)ai[i][j];  sb[2*i+1] = (h16)ar[i][j];
                }
                *(h16x8*)(sh + OFF_SAB + (l0+j)*44 + k0) = sa;
                *(h16x8*)(sh + OFF_SBA + (l0+j)*44 + k0) = sb;
            }
        }
        __syncthreads();                                   // (1)

        // ---- coefficients: 4 lanes per user k (column k of S^T); scale in place
        if (tid < 160) {
            const int k = tid >> 2, q = tid & 3;
            h16x2 va[10], vb[10];
            #pragma unroll
            for (int ii = 0; ii < 10; ++ii)
                va[ii] = sh[OFF_SAB + (q*10+ii)*44 + k];
            float rs = 0.f, d = 0.f;
            #pragma unroll
            for (int ii = 0; ii < 10; ++ii) rs = DOT2(va[ii], va[ii], rs);
            const int dk = k - q*10;
            if (dk >= 0 && dk < 10) d = DOT2(va[dk], va[dk], 0.f);
            rs += __shfl_xor(rs, 1, 64); rs += __shfl_xor(rs, 2, 64);
            d  += __shfl_xor(d , 1, 64); d  += __shfl_xor(d , 2, 64);
            float T  = rs + SIGMA;
            float Is = rs - d + SIGMA;
            float cA = 2.f * INVLN2 / T;
            float cC = -2.f * INVLN2 * d / (Is * T);
            #pragma unroll
            for (int ii = 0; ii < 10; ++ii)
                vb[ii] = sh[OFF_SBA + (q*10+ii)*44 + k];
            h16x2 cvA = PK(cA, cA), cvC = PK(cC, cC);
            #pragma unroll
            for (int ii = 0; ii < 10; ++ii) {
                h16x2 c = ((q*10+ii) == k) ? cvA : cvC;
                sh[OFF_SAB + (q*10+ii)*44 + k] = va[ii] * c;
                sh[OFF_SBA + (q*10+ii)*44 + k] = vb[ii] * c;
            }
        }
        __syncthreads();                                   // (2)

        // ---- B: G = H @ S' - cp*W  (tile 2n x 5c; W from regs)
        float gr[2][5] = {}, gi[2][5] = {};
        #pragma unroll 2
        for (int kb = 0; kb < 10; ++kb) {
            h16x8 hA = *(const h16x8*)(sh + OFF_H + (n0  )*44 + kb*4);
            h16x8 hB = *(const h16x8*)(sh + OFF_H + (n0+1)*44 + kb*4);
            #pragma unroll
            for (int j = 0; j < 5; ++j) {
                h16x8 sa = *(const h16x8*)(sh + OFF_SAB + (c0+j)*44 + kb*4);
                h16x8 sb = *(const h16x8*)(sh + OFF_SBA + (c0+j)*44 + kb*4);
                #pragma unroll
                for (int kk = 0; kk < 4; ++kk) {
                    h16x2 s1 = GET8(sa,kk), s2 = GET8(sb,kk);
                    h16x2 a_ = GET8(hA,kk), b_ = GET8(hB,kk);
                    gr[0][j] = DOT2(a_, s1, gr[0][j]);
                    gi[0][j] = DOT2(a_, s2, gi[0][j]);
                    gr[1][j] = DOT2(b_, s1, gr[1][j]);
                    gi[1][j] = DOT2(b_, s2, gi[1][j]);
                }
            }
        }
        #pragma unroll
        for (int i = 0; i < 2; ++i)
            #pragma unroll
            for (int j = 0; j < 5; ++j) {
                gr[i][j] -= cp * Wr[i][j];
                gi[i][j] -= cp * Wi[i][j];
            }
        __syncthreads();                                   // (3) S reads done

        // G (m-pair packed, transposed) into dead S region; U[t] into sUp
        #pragma unroll
        for (int j = 0; j < 5; ++j) {
            sh[OFF_SAB + (c0+j)*34 + nn0] = PK(gr[0][j], gr[1][j]);
            sh[OFF_SBA + (c0+j)*34 + nn0] = PK(gi[0][j], gi[1][j]);
        }
        #pragma unroll
        for (int j = 0; j < 8; ++j) {
            int e = tid + j*256;                 // (n, mm)
            int n = e >> 5, mm = e & 31;
            sh[OFF_UP + n*33 + mm] = PK(ureg[j].x, ureg[j].y);
        }
        __syncthreads();                                   // (4) G, U visible

        // ---- C: Ug = U @ G; W update in regs; power fold; packed W -> LDS
        {
            float ur[2][5] = {}, ui[2][5] = {};
            #pragma unroll 2
            for (int mb = 0; mb < 16; ++mb) {
                const int mm0 = 2*mb;
                h16x4 u0v = *(const h16x4*)(sh + OFF_UP + (n0  )*33 + mm0);
                h16x4 u1v = *(const h16x4*)(sh + OFF_UP + (n0+1)*33 + mm0);
                h16x2 u0a = GET4(u0v,0), u0b = GET4(u0v,1);
                h16x2 u1a = GET4(u1v,0), u1b = GET4(u1v,1);
                #pragma unroll
                for (int j = 0; j < 5; ++j) {
                    h16x4 gv = *(const h16x4*)(sh + OFF_SAB + (c0+j)*34 + mm0);
                    h16x4 qv = *(const h16x4*)(sh + OFF_SBA + (c0+j)*34 + mm0);
                    h16x2 g0 = GET4(gv,0), g1 = GET4(gv,1);
                    h16x2 q0 = GET4(qv,0), q1 = GET4(qv,1);
                    ur[0][j] = DOT2(u0a, g0, DOT2(u0b, g1, ur[0][j]));
                    ui[0][j] = DOT2(u0a, q0, DOT2(u0b, q1, ui[0][j]));
                    ur[1][j] = DOT2(u1a, g0, DOT2(u1b, g1, ur[1][j]));
                    ui[1][j] = DOT2(u1a, q0, DOT2(u1b, q1, ui[1][j]));
                }
            }
            float ps2 = 0.f;
            #pragma unroll
            for (int i = 0; i < 2; ++i)
                #pragma unroll
                for (int j = 0; j < 5; ++j) {
                    float stepr = ur[i][j] - ui[i][j];
                    float stepi = ui[i][j] + ur[i][j];
                    float wr = Wr[i][j] - etat*stepr + breg[i][j];
                    float wi = Wi[i][j] - etat*stepi;
                    Wr[i][j] = wr; Wi[i][j] = wi;
                    sh[OFF_WAB + (n0+i)*40 + c0+j] = PK(wr,  wi);
                    sh[OFF_WBA + (n0+i)*40 + c0+j] = PK(wi, -wr);
                    ps2 += wr*wr + wi*wi;
                }
            #pragma unroll
            for (int off = 32; off; off >>= 1) ps2 += __shfl_down(ps2, off, 64);
            if ((tid & 63) == 0) sRed[wid] = ps2;
        }
        __syncthreads();                                   // (5)
    }

    // ---- final normalization from registers
    const float pwf   = sRed[0] + sRed[1] + sRed[2] + sRed[3];
    const float scale = 1.0f / (sqrtf(pwf) + 1e-6f);

    if (outFloats >= 2 * NBATCH * NT * KK) {
        float2* ob = (float2*)(gOut + (size_t)bb * NT * KK * 2);
        #pragma unroll
        for (int i = 0; i < 2; ++i)
            #pragma unroll
            for (int j = 0; j < 5; ++j) {
                float2 v; v.x = Wr[i][j]*scale; v.y = Wi[i][j]*scale;
                ob[(n0+i)*KK + c0 + j] = v;
            }
    } else {
        float* ob = gOut + (size_t)bb * NT * KK;
        #pragma unroll
        for (int i = 0; i < 2; ++i)
            #pragma unroll
            for (int j = 0; j < 5; ++j)
                ob[(n0+i)*KK + c0 + j] = Wr[i][j] * scale;
    }
}

extern "C" void kernel_launch(void* const* d_in, const int* in_sizes, int n_in,
                              void* d_out, int out_size, void* d_ws, size_t ws_size,
                              hipStream_t stream) {
    (void)in_sizes; (void)n_in; (void)d_ws; (void)ws_size;
    const float* Hr  = (const float*)d_in[0];
    const float* Hi  = (const float*)d_in[1];
    const float* eta = (const float*)d_in[2];
    const float* U   = (const float*)d_in[3];
    const float* b   = (const float*)d_in[4];
    float* out = (float*)d_out;
    gpnet_kernel<<<NBATCH, 256, 0, stream>>>(Hr, Hi, eta, U, b, out, out_size);
}

// Round 7
// 329.167 us; speedup vs baseline: 1.1158x; 1.1158x over previous
//
#include <hip/hip_runtime.h>
#include <math.h>

typedef _Float16 h16;
typedef __attribute__((ext_vector_type(2))) _Float16 h16x2;
typedef __attribute__((ext_vector_type(4))) _Float16 h16x4;
typedef __attribute__((ext_vector_type(8))) _Float16 h16x8;

#define NBATCH 2048
#define NT 64
#define KK 40
#define NL 7
#define SIGMA 0.02f
#define INVLN2 1.4426950408889634f

// LDS layout (units: h16x2 = 4B). Target: <= ~42.6 KB -> 3 blocks/CU
// (observed effective workgroup-LDS pool ~128 KiB, not 160).
#define OFF_H   0                   // H  [64][40]  (hr,hi), k-contiguous
#define OFF_WAB (64*40)             // W  [64][40]  (wr,wi)  (single copy)
#define OFF_SAB (OFF_WAB + 64*40)   // S^T[40][44]  (sr,-si); G overlay [40][34] (gr pairs)
#define OFF_SBA (OFF_SAB + 40*44)   // S^T[40][44]  (si, sr); G overlay [40][34] (gi pairs)
#define OFF_UP  (OFF_SBA + 40*44)   // U  [64][34]  (u[m],u[m+1]) packed m-pairs
#define LDS_H2  (OFF_UP + 64*34)    // = 10816 pairs = 43264 B

static __device__ __forceinline__ float DOT2(h16x2 a, h16x2 b, float c) {
#if __has_builtin(__builtin_amdgcn_fdot2)
    return __builtin_amdgcn_fdot2(a, b, c, false);
#else
    return fmaf((float)a.x, (float)b.x, fmaf((float)a.y, (float)b.y, c));
#endif
}
static __device__ __forceinline__ h16x2 PK(float x, float y) {
    h16x2 r; r.x = (h16)x; r.y = (h16)y; return r;
}
// (wr,wi) -> (wi,-wr): swap 16-bit halves, then flip sign bit of high half.
static __device__ __forceinline__ h16x2 SWNH(h16x2 w) {
    unsigned u = __builtin_bit_cast(unsigned, w);
    u = (u >> 16) | (u << 16);
    u ^= 0x80000000u;
    return __builtin_bit_cast(h16x2, u);
}
// pair extractors: all call sites fully unrolled -> indices constant-fold (SROA keeps regs)
static __device__ __forceinline__ h16x2 GET8(h16x8 v, int i) {
    union { h16x8 w; h16x2 p[4]; } u; u.w = v; return u.p[i];
}
static __device__ __forceinline__ h16x2 GET4(h16x4 v, int i) {
    union { h16x4 w; h16x2 p[2]; } u; u.w = v; return u.p[i];
}

__global__ __launch_bounds__(256, 3) void gpnet_kernel(
    const float* __restrict__ gHr, const float* __restrict__ gHi,
    const float* __restrict__ gEta, const float* __restrict__ gU,
    const float* __restrict__ gB, float* __restrict__ gOut, int outFloats)
{
    __shared__ __align__(16) h16x2 sh[LDS_H2];
    __shared__ float sRed[4];

    const int tid = threadIdx.x;
    const int wid = tid >> 6;
    const int bb  = blockIdx.x;
    const float* hr = gHr + (size_t)bb * NT * KK;
    const float* hi = gHi + (size_t)bb * NT * KK;

    // B/C/W-ownership tile: rows (n0, n0+1), cols c0..c0+4
    const int n0  = (tid >> 3) << 1;     // 0,2,...,62
    const int c0  = (tid & 7) * 5;       // 0,5,...,35
    const int nn0 = tid >> 3;            // m-pair index for G

    // A-phase tile (first 200 threads): S rows k0..k0+3, cols l0,l0+1
    const int k0 = (tid / 20) * 4;
    const int l0 = (tid % 20) * 2;

    // ---- init: H -> LDS (fp16 packed); W = b[0] in regs; packed W -> LDS; power
    float Wr[2][5], Wi[2][5];
    {
        for (int i = tid; i < NT*KK; i += 256) {
            int n = i / KK, k = i % KK;
            sh[OFF_H + n*40 + k] = PK(hr[i], hi[i]);
        }
        float ps = 0.f;
        #pragma unroll
        for (int i = 0; i < 2; ++i)
            #pragma unroll
            for (int j = 0; j < 5; ++j) {
                float br = gB[(n0+i)*KK + c0 + j];
                Wr[i][j] = br; Wi[i][j] = 0.f;
                sh[OFF_WAB + (n0+i)*40 + c0+j] = PK(br, 0.f);
                ps += br * br;
            }
        #pragma unroll
        for (int off = 32; off; off >>= 1) ps += __shfl_down(ps, off, 64);
        if ((tid & 63) == 0) sRed[wid] = ps;
    }
    __syncthreads();

    for (int t = 1; t < NL; ++t) {
        const float pw   = sRed[0] + sRed[1] + sRed[2] + sRed[3];
        const float cp   = 0.04f * (pw - 1.0f);
        const float etat = gEta[t];

        // early global loads (hidden under A/coeff/B): U[t] (float2 pairs) and b[t]
        float2 ureg[8];
        {
            const float2* u2 = (const float2*)(gU + (size_t)t * NT * NT);
            #pragma unroll
            for (int j = 0; j < 8; ++j) ureg[j] = u2[tid + j*256];
        }
        float breg[2][5];
        #pragma unroll
        for (int i = 0; i < 2; ++i)
            #pragma unroll
            for (int j = 0; j < 5; ++j)
                breg[i][j] = gB[(size_t)t*NT*KK + (n0+i)*KK + c0 + j];

        // ---- A: S[k][l] = sum_n conj(H[n,k]) W[n,l]; write S^T fp16 (two packed forms)
        if (tid < 200) {
            float ar[4][2] = {}, ai[4][2] = {};
            #pragma unroll 2
            for (int n = 0; n < NT; ++n) {
                h16x8 hv  = *(const h16x8*)(sh + OFF_H   + n*40 + k0);
                h16x4 wav = *(const h16x4*)(sh + OFF_WAB + n*40 + l0);
                h16x2 wa0 = GET4(wav,0), wa1 = GET4(wav,1);
                h16x2 wb0 = SWNH(wa0),   wb1 = SWNH(wa1);   // (wi,-wr)
                #pragma unroll
                for (int i = 0; i < 4; ++i) {
                    h16x2 h_ = GET8(hv,i);
                    ar[i][0] = DOT2(h_, wa0, ar[i][0]);   // hr*wr + hi*wi
                    ar[i][1] = DOT2(h_, wa1, ar[i][1]);
                    ai[i][0] = DOT2(h_, wb0, ai[i][0]);   // hr*wi - hi*wr
                    ai[i][1] = DOT2(h_, wb1, ai[i][1]);
                }
            }
            #pragma unroll
            for (int j = 0; j < 2; ++j) {
                h16x8 sa, sb;
                #pragma unroll
                for (int i = 0; i < 4; ++i) {
                    sa[2*i]   = (h16)ar[i][j];  sa[2*i+1] = (h16)(-ai[i][j]);
                    sb[2*i]   = (h16)ai[i][j];  sb[2*i+1] = (h16)ar[i][j];
                }
                *(h16x8*)(sh + OFF_SAB + (l0+j)*44 + k0) = sa;
                *(h16x8*)(sh + OFF_SBA + (l0+j)*44 + k0) = sb;
            }
        }
        __syncthreads();                                   // (1)

        // ---- coefficients: 4 lanes per user k (column k of S^T); scale in place
        if (tid < 160) {
            const int k = tid >> 2, q = tid & 3;
            h16x2 va[10], vb[10];
            #pragma unroll
            for (int ii = 0; ii < 10; ++ii)
                va[ii] = sh[OFF_SAB + (q*10+ii)*44 + k];
            float rs = 0.f, d = 0.f;
            #pragma unroll
            for (int ii = 0; ii < 10; ++ii) rs = DOT2(va[ii], va[ii], rs);
            const int dk = k - q*10;
            if (dk >= 0 && dk < 10) d = DOT2(va[dk], va[dk], 0.f);
            rs += __shfl_xor(rs, 1, 64); rs += __shfl_xor(rs, 2, 64);
            d  += __shfl_xor(d , 1, 64); d  += __shfl_xor(d , 2, 64);
            float T  = rs + SIGMA;
            float Is = rs - d + SIGMA;
            float cA = 2.f * INVLN2 / T;
            float cC = -2.f * INVLN2 * d / (Is * T);
            #pragma unroll
            for (int ii = 0; ii < 10; ++ii)
                vb[ii] = sh[OFF_SBA + (q*10+ii)*44 + k];
            h16x2 cvA = PK(cA, cA), cvC = PK(cC, cC);
            #pragma unroll
            for (int ii = 0; ii < 10; ++ii) {
                h16x2 c = ((q*10+ii) == k) ? cvA : cvC;
                sh[OFF_SAB + (q*10+ii)*44 + k] = va[ii] * c;
                sh[OFF_SBA + (q*10+ii)*44 + k] = vb[ii] * c;
            }
        }
        __syncthreads();                                   // (2)

        // ---- B: G = H @ S' - cp*W  (tile 2n x 5c; W from regs)
        float gr[2][5] = {}, gi[2][5] = {};
        #pragma unroll 2
        for (int kb = 0; kb < 10; ++kb) {
            h16x8 hA = *(const h16x8*)(sh + OFF_H + (n0  )*40 + kb*4);
            h16x8 hB = *(const h16x8*)(sh + OFF_H + (n0+1)*40 + kb*4);
            #pragma unroll
            for (int j = 0; j < 5; ++j) {
                h16x8 sa = *(const h16x8*)(sh + OFF_SAB + (c0+j)*44 + kb*4);
                h16x8 sb = *(const h16x8*)(sh + OFF_SBA + (c0+j)*44 + kb*4);
                #pragma unroll
                for (int kk = 0; kk < 4; ++kk) {
                    h16x2 s1 = GET8(sa,kk), s2 = GET8(sb,kk);
                    h16x2 a_ = GET8(hA,kk), b_ = GET8(hB,kk);
                    gr[0][j] = DOT2(a_, s1, gr[0][j]);
                    gi[0][j] = DOT2(a_, s2, gi[0][j]);
                    gr[1][j] = DOT2(b_, s1, gr[1][j]);
                    gi[1][j] = DOT2(b_, s2, gi[1][j]);
                }
            }
        }
        #pragma unroll
        for (int i = 0; i < 2; ++i)
            #pragma unroll
            for (int j = 0; j < 5; ++j) {
                gr[i][j] -= cp * Wr[i][j];
                gi[i][j] -= cp * Wi[i][j];
            }
        __syncthreads();                                   // (3) S reads done

        // G (m-pair packed, transposed) into dead S region; U[t] into sUp
        #pragma unroll
        for (int j = 0; j < 5; ++j) {
            sh[OFF_SAB + (c0+j)*34 + nn0] = PK(gr[0][j], gr[1][j]);
            sh[OFF_SBA + (c0+j)*34 + nn0] = PK(gi[0][j], gi[1][j]);
        }
        #pragma unroll
        for (int j = 0; j < 8; ++j) {
            int e = tid + j*256;                 // (n, mm)
            int n = e >> 5, mm = e & 31;
            sh[OFF_UP + n*34 + mm] = PK(ureg[j].x, ureg[j].y);
        }
        __syncthreads();                                   // (4) G, U visible

        // ---- C: Ug = U @ G; W update in regs; power fold; packed W -> LDS
        {
            float ur[2][5] = {}, ui[2][5] = {};
            #pragma unroll 2
            for (int mb = 0; mb < 16; ++mb) {
                const int mm0 = 2*mb;
                h16x4 u0v = *(const h16x4*)(sh + OFF_UP + (n0  )*34 + mm0);
                h16x4 u1v = *(const h16x4*)(sh + OFF_UP + (n0+1)*34 + mm0);
                h16x2 u0a = GET4(u0v,0), u0b = GET4(u0v,1);
                h16x2 u1a = GET4(u1v,0), u1b = GET4(u1v,1);
                #pragma unroll
                for (int j = 0; j < 5; ++j) {
                    h16x4 gv = *(const h16x4*)(sh + OFF_SAB + (c0+j)*34 + mm0);
                    h16x4 qv = *(const h16x4*)(sh + OFF_SBA + (c0+j)*34 + mm0);
                    h16x2 g0 = GET4(gv,0), g1 = GET4(gv,1);
                    h16x2 q0 = GET4(qv,0), q1 = GET4(qv,1);
                    ur[0][j] = DOT2(u0a, g0, DOT2(u0b, g1, ur[0][j]));
                    ui[0][j] = DOT2(u0a, q0, DOT2(u0b, q1, ui[0][j]));
                    ur[1][j] = DOT2(u1a, g0, DOT2(u1b, g1, ur[1][j]));
                    ui[1][j] = DOT2(u1a, q0, DOT2(u1b, q1, ui[1][j]));
                }
            }
            float ps2 = 0.f;
            #pragma unroll
            for (int i = 0; i < 2; ++i)
                #pragma unroll
                for (int j = 0; j < 5; ++j) {
                    float stepr = ur[i][j] - ui[i][j];
                    float stepi = ui[i][j] + ur[i][j];
                    float wr = Wr[i][j] - etat*stepr + breg[i][j];
                    float wi = Wi[i][j] - etat*stepi;
                    Wr[i][j] = wr; Wi[i][j] = wi;
                    sh[OFF_WAB + (n0+i)*40 + c0+j] = PK(wr, wi);
                    ps2 += wr*wr + wi*wi;
                }
            #pragma unroll
            for (int off = 32; off; off >>= 1) ps2 += __shfl_down(ps2, off, 64);
            if ((tid & 63) == 0) sRed[wid] = ps2;
        }
        __syncthreads();                                   // (5)
    }

    // ---- final normalization from registers
    const float pwf   = sRed[0] + sRed[1] + sRed[2] + sRed[3];
    const float scale = 1.0f / (sqrtf(pwf) + 1e-6f);

    if (outFloats >= 2 * NBATCH * NT * KK) {
        float2* ob = (float2*)(gOut + (size_t)bb * NT * KK * 2);
        #pragma unroll
        for (int i = 0; i < 2; ++i)
            #pragma unroll
            for (int j = 0; j < 5; ++j) {
                float2 v; v.x = Wr[i][j]*scale; v.y = Wi[i][j]*scale;
                ob[(n0+i)*KK + c0 + j] = v;
            }
    } else {
        float* ob = gOut + (size_t)bb * NT * KK;
        #pragma unroll
        for (int i = 0; i < 2; ++i)
            #pragma unroll
            for (int j = 0; j < 5; ++j)
                ob[(n0+i)*KK + c0 + j] = Wr[i][j] * scale;
    }
}

extern "C" void kernel_launch(void* const* d_in, const int* in_sizes, int n_in,
                              void* d_out, int out_size, void* d_ws, size_t ws_size,
                              hipStream_t stream) {
    (void)in_sizes; (void)n_in; (void)d_ws; (void)ws_size;
    const float* Hr  = (const float*)d_in[0];
    const float* Hi  = (const float*)d_in[1];
    const float* eta = (const float*)d_in[2];
    const float* U   = (const float*)d_in[3];
    const float* b   = (const float*)d_in[4];
    float* out = (float*)d_out;
    gpnet_kernel<<<NBATCH, 256, 0, stream>>>(Hr, Hi, eta, U, b, out, out_size);
}

// Round 11
// 257.238 us; speedup vs baseline: 1.4278x; 1.2796x over previous
//
#include <hip/hip_runtime.h>
#include <math.h>

typedef _Float16 h16;
typedef __attribute__((ext_vector_type(2))) _Float16 h16x2;
typedef __attribute__((ext_vector_type(8))) _Float16 h16x8;
typedef __attribute__((ext_vector_type(4))) float f32x4;

#define NBATCH 2048
#define NT 64
#define KK 40
#define NL 7
#define SIGMA 0.02f
#define INVLN2 1.4426950408889634f

// LDS offsets in h16 units. Row stride 128 h16 (256 B) except U/G-planes (64).
// All arrays XOR-swizzled: h16-col ^= (row&7)<<3 (write AND read sides).
#define WT   0                    // W^T packed (wr,wi): [48 l][128 c=2n+ri]
#define HCK  (48*128)             // H^H packed: [48 k][128 c=2n+ri] (hr,hi)
#define HNC  (HCK + 48*128)       // H interleaved: [64 n][96 c=2k+ri pad 128]
#define B2T  (HNC + 64*128)       // S then S' packed [48 l][96 c=2k+ri]
#define GRE  B2T                  // overlay after barrier: G_re plane [48 l][64 m]
#define GIM  (B2T + 48*64)        // overlay: G_im plane [48 l][64 m]
#define UOF  (B2T + 48*128)       // U [64 n][64 m] f16
#define LDSH (UOF + 64*64)        // 30720 h16 = 61440 B -> 2 blocks/CU

#define SWZ(row, c) ((c) ^ (((row)&7)<<3))
#define MFMA16(a,b,c) __builtin_amdgcn_mfma_f32_16x16x32_f16((a),(b),(c),0,0,0)

static __device__ __forceinline__ float DOT2(h16x2 a, h16x2 b, float c) {
#if __has_builtin(__builtin_amdgcn_fdot2)
    return __builtin_amdgcn_fdot2(a, b, c, false);
#else
    return fmaf((float)a.x, (float)b.x, fmaf((float)a.y, (float)b.y, c));
#endif
}
static __device__ __forceinline__ h16x2 PK(float x, float y) {
    h16x2 r; r.x = (h16)x; r.y = (h16)y; return r;
}
// (wr,wi) -> (wi,-wr)
static __device__ __forceinline__ h16x2 SWNH(h16x2 w) {
    unsigned u = __builtin_bit_cast(unsigned, w);
    u = (u >> 16) | (u << 16);
    u ^= 0x80000000u;
    return __builtin_bit_cast(h16x2, u);
}
// per 32b word (sr',-si') -> (si',sr')
static __device__ __forceinline__ h16x8 imB(h16x8 v) {
    union { h16x8 h; unsigned u[4]; } x; x.h = v;
    #pragma unroll
    for (int i=0;i<4;++i){ unsigned t=x.u[i]; t=(t>>16)|(t<<16); x.u[i]=t^0x00008000u; }
    return x.h;
}
static __device__ __forceinline__ h16x2 GET8(h16x8 v, int i) {
    union { h16x8 w; h16x2 p[4]; } u; u.w = v; return u.p[i];
}

__global__ __launch_bounds__(256, 2) void gpnet_kernel(
    const float* __restrict__ gHr, const float* __restrict__ gHi,
    const float* __restrict__ gEta, const float* __restrict__ gU,
    const float* __restrict__ gB, float* __restrict__ gOut, int outFloats)
{
    __shared__ __align__(16) h16 sh[LDSH];
    __shared__ float sRed[4];

    const int tid = threadIdx.x;
    const int wv  = tid >> 6;      // wave 0..3
    const int ln  = tid & 63;
    const int col = ln & 15;       // fragment col / row component
    const int g   = ln >> 4;       // k-group

    const int bb = blockIdx.x;
    const float* hr = gHr + (size_t)bb * NT * KK;
    const float* hi = gHi + (size_t)bb * NT * KK;

    // ---- init: zero pads
    for (int i = tid; i < 512; i += 256) {
        *(h16x2*)(sh + WT  + 40*128 + 2*i) = PK(0.f, 0.f);   // Wt rows 40..47
        *(h16x2*)(sh + HCK + 40*128 + 2*i) = PK(0.f, 0.f);   // Hck rows 40..47
    }
    for (int i = tid; i < 512; i += 256) {                   // Hnc logical cols [80,96)
        int n = i >> 3, c = 80 + 2*(i & 7);
        *(h16x2*)(sh + HNC + n*128 + SWZ(n, c)) = PK(0.f, 0.f);
    }
    // H data (both layouts) + W^T = b0  (layer-0 collapse: W1 = b[0], Wi = 0)
    for (int i = tid; i < NT*KK; i += 256) {
        int n = i / KK, k = i % KK;
        float xr = hr[i], xi = hi[i];
        h16x2 p = PK(xr, xi);
        *(h16x2*)(sh + HCK + k*128 + SWZ(k, 2*n)) = p;
        *(h16x2*)(sh + HNC + n*128 + SWZ(n, 2*k)) = p;
        *(h16x2*)(sh + WT  + k*128 + SWZ(k, 2*n)) = PK(gB[i], 0.f);
    }
    // W-cache (f32 regs) = b0 at owned positions; power
    float Wr[3][4], Wi[3][4];
    float ps = 0.f;
    #pragma unroll
    for (int ct = 0; ct < 3; ++ct)
        #pragma unroll
        for (int r = 0; r < 4; ++r) {
            int n = 16*wv + 4*g + r, l = col + 16*ct;
            float b0 = (l < KK) ? gB[n*KK + l] : 0.f;
            Wr[ct][r] = b0; Wi[ct][r] = 0.f;
            ps += b0 * b0;
        }
    #pragma unroll
    for (int off = 32; off; off >>= 1) ps += __shfl_down(ps, off, 64);
    if (ln == 0) sRed[wv] = ps;
    __syncthreads();

    for (int t = 1; t < NL; ++t) {
        const float pw   = sRed[0] + sRed[1] + sRed[2] + sRed[3];
        const float cpen = 0.04f * (pw - 1.0f);
        const float etat = gEta[t];

        // early global loads: U[t] pairs and b[t] at owned positions
        float2 ureg[8];
        {
            const float2* u2 = (const float2*)(gU + (size_t)t * NT * NT);
            #pragma unroll
            for (int j = 0; j < 8; ++j) ureg[j] = u2[tid + j*256];
        }
        float breg[3][4];
        #pragma unroll
        for (int ct = 0; ct < 3; ++ct)
            #pragma unroll
            for (int r = 0; r < 4; ++r) {
                int n = 16*wv + 4*g + r, l = col + 16*ct;
                breg[ct][r] = (l < KK) ? gB[(size_t)t*NT*KK + n*KK + l] : 0.f;
            }

        // ---- PHASE A (scalar dot2 bisect): pad-zero B2T, then 4k x 2l tiles
        // pads: rows 40..47 (48 cols) + rows 0..39 cols k=40..47  (GIM overlay
        // dirtied these last layer; phase B reads them as S' -> must be 0)
        for (int e = tid; e < 704; e += 256) {
            int l, k;
            if (e < 384) { l = 40 + e / 48; k = e % 48; }
            else { int f = e - 384; l = f >> 3; k = 40 + (f & 7); }
            *(h16x2*)(sh + B2T + l*128 + SWZ(l, 2*k)) = PK(0.f, 0.f);
        }
        if (tid < 200) {
            const int k0 = (tid / 20) * 4;
            const int l0 = (tid % 20) * 2;
            float ar[4][2] = {}, ai[4][2] = {};
            #pragma unroll 4
            for (int c = 0; c < 16; ++c) {
                h16x8 w0 = *(const h16x8*)(sh + WT + (l0  )*128 + SWZ(l0,   c*8));
                h16x8 w1 = *(const h16x8*)(sh + WT + (l0+1)*128 + SWZ(l0+1, c*8));
                #pragma unroll
                for (int i = 0; i < 4; ++i) {
                    h16x8 hv = *(const h16x8*)(sh + HCK + (k0+i)*128 + SWZ(k0+i, c*8));
                    #pragma unroll
                    for (int wd = 0; wd < 4; ++wd) {
                        h16x2 hp  = GET8(hv, wd);
                        h16x2 wp0 = GET8(w0, wd), wp1 = GET8(w1, wd);
                        ar[i][0] = DOT2(wp0, hp, ar[i][0]);        // Re
                        ai[i][0] = DOT2(SWNH(wp0), hp, ai[i][0]);  // Im
                        ar[i][1] = DOT2(wp1, hp, ar[i][1]);
                        ai[i][1] = DOT2(SWNH(wp1), hp, ai[i][1]);
                    }
                }
            }
            // UNSCALED S^T: (sr, si) at row l, col 2k
            #pragma unroll
            for (int i = 0; i < 4; ++i)
                #pragma unroll
                for (int j = 0; j < 2; ++j)
                    *(h16x2*)(sh + B2T + (l0+j)*128 + SWZ(l0+j, 2*(k0+i))) =
                        PK(ar[i][j], ai[i][j]);
        }
        __syncthreads();                       // (1) unscaled S ready

        // ---- coefficients (round-7 port): 4 lanes per user k; scale column k
        if (tid < 160) {
            const int k = tid >> 2, q = tid & 3;
            h16x2 va[10];
            #pragma unroll
            for (int ii = 0; ii < 10; ++ii)
                va[ii] = *(const h16x2*)(sh + B2T + (q*10+ii)*128 + SWZ(q*10+ii, 2*k));
            float rs = 0.f, dd = 0.f;
            #pragma unroll
            for (int ii = 0; ii < 10; ++ii) rs = DOT2(va[ii], va[ii], rs);
            const int dk = k - q*10;
            if (dk >= 0 && dk < 10) dd = DOT2(va[dk], va[dk], 0.f);
            rs += __shfl_xor(rs, 1, 64); rs += __shfl_xor(rs, 2, 64);
            dd += __shfl_xor(dd, 1, 64); dd += __shfl_xor(dd, 2, 64);
            float T  = rs + SIGMA, Is = rs - dd + SIGMA;
            float cA_ = 2.f * INVLN2 / T;
            float cC_ = -2.f * INVLN2 * dd / (Is * T);
            #pragma unroll
            for (int ii = 0; ii < 10; ++ii) {
                int l = q*10 + ii;
                float c = (l == k) ? cA_ : cC_;
                *(h16x2*)(sh + B2T + l*128 + SWZ(l, 2*k)) =
                    PK((float)va[ii].x * c, -(float)va[ii].y * c);   // (sr',-si')
            }
        }
        __syncthreads();                       // (2) S' ready

        // ---- PHASE B (MFMA): G[n][l], row-strip n in [16wv,16wv+16)
        f32x4 gRe[3], gIm[3];
        #pragma unroll
        for (int ct = 0; ct < 3; ++ct) { gRe[ct] = (f32x4){0.f,0.f,0.f,0.f}; gIm[ct] = (f32x4){0.f,0.f,0.f,0.f}; }
        {
            const int nrow = col + 16*wv;
            #pragma unroll
            for (int q = 0; q < 3; ++q) {
                h16x8 af = *(const h16x8*)(sh + HNC + nrow*128 + SWZ(nrow, g*8 + 32*q));
                #pragma unroll
                for (int ct = 0; ct < 3; ++ct) {
                    int lr = col + 16*ct;
                    h16x8 bf = *(const h16x8*)(sh + B2T + lr*128 + SWZ(lr, g*8 + 32*q));
                    gRe[ct] = MFMA16(af, bf, gRe[ct]);
                    gIm[ct] = MFMA16(af, imB(bf), gIm[ct]);
                }
            }
        }
        #pragma unroll
        for (int ct = 0; ct < 3; ++ct)
            #pragma unroll
            for (int r = 0; r < 4; ++r) {
                gRe[ct][r] -= cpen * Wr[ct][r];
                gIm[ct][r] -= cpen * Wi[ct][r];
            }
        // U[t] -> LDS (disjoint region; read by phase C after barrier 4)
        #pragma unroll
        for (int j = 0; j < 8; ++j) {
            int e2 = tid + j*256;
            int n = e2 >> 5, m2 = (e2 & 31) * 2;
            *(h16x2*)(sh + UOF + n*64 + SWZ(n, m2)) = PK(ureg[j].x, ureg[j].y);
        }
        __syncthreads();                       // (3) all B2t reads done
        // write G as split planes GRE[l][m], GIM[l][m] (m = antenna n)
        #pragma unroll
        for (int ct = 0; ct < 3; ++ct)
            #pragma unroll
            for (int r = 0; r < 4; ++r) {
                int n = 16*wv + 4*g + r, l = col + 16*ct;
                sh[GRE + l*64 + SWZ(l, n)] = (h16)gRe[ct][r];
                sh[GIM + l*64 + SWZ(l, n)] = (h16)gIm[ct][r];
            }
        __syncthreads();                       // (4) G planes + U visible

        // ---- PHASE C (MFMA): Ug = U x G ; W update; power fold
        f32x4 cRe[3], cIm[3];
        #pragma unroll
        for (int ct = 0; ct < 3; ++ct) { cRe[ct] = (f32x4){0.f,0.f,0.f,0.f}; cIm[ct] = (f32x4){0.f,0.f,0.f,0.f}; }
        {
            const int nrow = col + 16*wv;
            #pragma unroll
            for (int q = 0; q < 2; ++q) {
                h16x8 af = *(const h16x8*)(sh + UOF + nrow*64 + SWZ(nrow, g*8 + 32*q));
                #pragma unroll
                for (int ct = 0; ct < 3; ++ct) {
                    const int l = col + 16*ct;
                    h16x8 fre = *(const h16x8*)(sh + GRE + l*64 + SWZ(l, g*8 + 32*q));
                    h16x8 fim = *(const h16x8*)(sh + GIM + l*64 + SWZ(l, g*8 + 32*q));
                    cRe[ct] = MFMA16(af, fre, cRe[ct]);
                    cIm[ct] = MFMA16(af, fim, cIm[ct]);
                }
            }
        }
        float ps2 = 0.f;
        #pragma unroll
        for (int ct = 0; ct < 3; ++ct)
            #pragma unroll
            for (int r = 0; r < 4; ++r) {
                int n = 16*wv + 4*g + r, l = col + 16*ct;
                float ur = cRe[ct][r], ui = cIm[ct][r];
                float wr = Wr[ct][r] - etat*(ur - ui) + breg[ct][r];
                float wi = Wi[ct][r] - etat*(ui + ur);
                Wr[ct][r] = wr; Wi[ct][r] = wi;
                if (l < KK) {
                    *(h16x2*)(sh + WT + l*128 + SWZ(l, 2*n)) = PK(wr, wi);
                    ps2 += wr*wr + wi*wi;
                }
            }
        #pragma unroll
        for (int off = 32; off; off >>= 1) ps2 += __shfl_down(ps2, off, 64);
        if (ln == 0) sRed[wv] = ps2;
        __syncthreads();                       // (5) Wt + sRed ready
    }

    // ---- final normalization from registers
    const float pwf   = sRed[0] + sRed[1] + sRed[2] + sRed[3];
    const float scale = 1.0f / (sqrtf(pwf) + 1e-6f);

    if (outFloats >= 2 * NBATCH * NT * KK) {
        float2* ob = (float2*)(gOut + (size_t)bb * NT * KK * 2);
        #pragma unroll
        for (int ct = 0; ct < 3; ++ct)
            #pragma unroll
            for (int r = 0; r < 4; ++r) {
                int n = 16*wv + 4*g + r, l = col + 16*ct;
                if (l < KK) {
                    float2 v; v.x = Wr[ct][r]*scale; v.y = Wi[ct][r]*scale;
                    ob[n*KK + l] = v;
                }
            }
    } else {
        float* ob = gOut + (size_t)bb * NT * KK;
        #pragma unroll
        for (int ct = 0; ct < 3; ++ct)
            #pragma unroll
            for (int r = 0; r < 4; ++r) {
                int n = 16*wv + 4*g + r, l = col + 16*ct;
                if (l < KK) ob[n*KK + l] = Wr[ct][r] * scale;
            }
    }
}

extern "C" void kernel_launch(void* const* d_in, const int* in_sizes, int n_in,
                              void* d_out, int out_size, void* d_ws, size_t ws_size,
                              hipStream_t stream) {
    (void)in_sizes; (void)n_in; (void)d_ws; (void)ws_size;
    const float* Hr  = (const float*)d_in[0];
    const float* Hi  = (const float*)d_in[1];
    const float* eta = (const float*)d_in[2];
    const float* U   = (const float*)d_in[3];
    const float* b   = (const float*)d_in[4];
    float* out = (float*)d_out;
    gpnet_kernel<<<NBATCH, 256, 0, stream>>>(Hr, Hi, eta, U, b, out, out_size);
}